// Round 6
// baseline (55.707 us; speedup 1.0000x reference)
//
#include <hip/hip_runtime.h>

#define NCLS 1000
#define NDF  256
#define BB   512
#define BN   16
#define NBLK 63   // 63*16 = 1008 >= 1000 columns

typedef __attribute__((ext_vector_type(8))) short short8;
typedef __attribute__((ext_vector_type(4))) float floatx4;

static __device__ __forceinline__ unsigned short f2bf(float f) {
    unsigned int u = __float_as_uint(f);
    u += 0x7FFFu + ((u >> 16) & 1u);   // RNE
    return (unsigned short)(u >> 16);
}

static __device__ __forceinline__ short8 cvt8(float4 a, float4 b) {
    short8 r;
    r[0] = (short)f2bf(a.x); r[1] = (short)f2bf(a.y);
    r[2] = (short)f2bf(a.z); r[3] = (short)f2bf(a.w);
    r[4] = (short)f2bf(b.x); r[5] = (short)f2bf(b.y);
    r[6] = (short)f2bf(b.z); r[7] = (short)f2bf(b.w);
    return r;
}

// One kernel does everything. Block b owns output columns j0=b*16..j0+15 for
// ALL 512 rows, so the combine step (which mixes rows s of the same class) is
// block-local. Cross-column terms G[.][t] reduce to per-sample scalars
// v[i] = df[i].fc[gt[i]] computed redundantly per block.
__global__ __launch_bounds__(512) void fused_all(
    const float* __restrict__ df, const int* __restrict__ gt,
    const float* __restrict__ fc, float* __restrict__ out)
{
    __shared__ int   s_gt[BB];
    __shared__ short s_occ[BB];    // 1-based occurrence index of row i
    __shared__ short s_prev[BB];   // previous occurrence step of same class (-1)
    __shared__ float s_v[BB];      // v[i] = df[i].fc[gt[i]]
    __shared__ float Gs[BB][BN + 1];  // G column tile, pad 17 (odd stride)

    int tid = threadIdx.x;
    int j0 = blockIdx.x * BN;

    s_gt[tid] = gt[tid];
    __syncthreads();

    // --- occurrence structure (per-row; LDS reads broadcast across lanes) ---
    int t_i = s_gt[tid];
    {
        int n = 0, prev = -1;
        for (int k = 0; k < tid; ++k)
            if (s_gt[k] == t_i) { ++n; prev = k; }
        s_occ[tid]  = (short)(n + 1);
        s_prev[tid] = (short)prev;
    }
    // --- v[i] (fp32 dot, own row) ---
    {
        const float* dp = df + (size_t)tid * NDF;
        const float* fp = fc + (size_t)t_i * NDF;
        float a = 0.f;
#pragma unroll 8
        for (int k = 0; k < NDF; k += 4) {
            float4 x = *(const float4*)(dp + k);
            float4 y = *(const float4*)(fp + k);
            a += x.x * y.x + x.y * y.y + x.z * y.z + x.w * y.w;
        }
        s_v[tid] = a;
    }

    // --- GEMM: Gs[r][jl] = df[r].fc[j0+jl], bf16 MFMA, fp32 acc ---
    // wave w owns rows w*64..w*64+63 (4 row-fragments). Fragment mapping
    // (verified in R5): A lane l -> row l&15, k-off (l>>4)*8; B mirrors with
    // col l&15. OOB columns clamp to fc row 999 (finite garbage, never stored).
    int lane = tid & 63, w = tid >> 6;
    int lr = lane & 15;
    int ksub = (lane >> 4) * 8;
    int jb = j0 + lr; if (jb > NCLS - 1) jb = NCLS - 1;
    const float* bp  = fc + (size_t)jb * NDF + ksub;
    const float* ap0 = df + (size_t)(w * 64 + lr) * NDF + ksub;

    floatx4 acc0 = {0.f,0.f,0.f,0.f}, acc1 = acc0, acc2 = acc0, acc3 = acc0;
#pragma unroll
    for (int c = 0; c < 8; ++c) {
        int kb = c * 32;
        short8 bf = cvt8(*(const float4*)(bp + kb), *(const float4*)(bp + kb + 4));
        short8 a0 = cvt8(*(const float4*)(ap0 + kb),            *(const float4*)(ap0 + kb + 4));
        short8 a1 = cvt8(*(const float4*)(ap0 + 16*NDF + kb),   *(const float4*)(ap0 + 16*NDF + kb + 4));
        short8 a2 = cvt8(*(const float4*)(ap0 + 32*NDF + kb),   *(const float4*)(ap0 + 32*NDF + kb + 4));
        short8 a3 = cvt8(*(const float4*)(ap0 + 48*NDF + kb),   *(const float4*)(ap0 + 48*NDF + kb + 4));
        acc0 = __builtin_amdgcn_mfma_f32_16x16x32_bf16(a0, bf, acc0, 0, 0, 0);
        acc1 = __builtin_amdgcn_mfma_f32_16x16x32_bf16(a1, bf, acc1, 0, 0, 0);
        acc2 = __builtin_amdgcn_mfma_f32_16x16x32_bf16(a2, bf, acc2, 0, 0, 0);
        acc3 = __builtin_amdgcn_mfma_f32_16x16x32_bf16(a3, bf, acc3, 0, 0, 0);
    }
    {
        // C/D layout: col = lane&15, row = (lane>>4)*4 + reg  [m89-verified]
        int rb = w * 64 + (lane >> 4) * 4;
#pragma unroll
        for (int r = 0; r < 4; ++r) Gs[rb +  0 + r][lr] = acc0[r];
#pragma unroll
        for (int r = 0; r < 4; ++r) Gs[rb + 16 + r][lr] = acc1[r];
#pragma unroll
        for (int r = 0; r < 4; ++r) Gs[rb + 32 + r][lr] = acc2[r];
#pragma unroll
        for (int r = 0; r < 4; ++r) Gs[rb + 48 + r][lr] = acc3[r];
    }
    __syncthreads();

    // --- combine: row i = tid, 16 columns.
    // out(i,j) = (G[i][j]-v[i]) + 0.05*sum_{m=2..n} (m-1)/(m*n) * (h_m[j]-h_m[t])^2
    // h_m[j] = G[s_m][j] - P_m[j]/m, P_m = prefix sum over first m occurrence
    // steps of class gt[i]; computed via backward prevOcc walk: P_m = T - suffix.
    {
        int i = tid;
        int n = (int)s_occ[i];
        float vi = s_v[i];
        float res[BN];
#pragma unroll
        for (int jl = 0; jl < BN; ++jl) res[jl] = Gs[i][jl] - vi;
        if (n >= 2) {
            float T[BN], S[BN], q[BN];
#pragma unroll
            for (int jl = 0; jl < BN; ++jl) { T[jl] = 0.f; S[jl] = 0.f; q[jl] = 0.f; }
            float Tv = 0.f, Sv = 0.f;
            int s = i;
            for (int m = n; m >= 1; --m) {          // total sums over s_1..s_n
#pragma unroll
                for (int jl = 0; jl < BN; ++jl) T[jl] += Gs[s][jl];
                Tv += s_v[s];
                s = s_prev[s];
            }
            float invn = 1.f / (float)n;
            s = i;
            for (int m = n; m >= 2; --m) {          // visit s_n..s_2
                float inv_m = 1.f / (float)m;
                float coef = (float)(m - 1) * inv_m * invn;
                float ht = s_v[s] - (Tv - Sv) * inv_m;
#pragma unroll
                for (int jl = 0; jl < BN; ++jl) {
                    float h = (Gs[s][jl] - (T[jl] - S[jl]) * inv_m) - ht;
                    q[jl] += coef * h * h;
                }
                Sv += s_v[s];
#pragma unroll
                for (int jl = 0; jl < BN; ++jl) S[jl] += Gs[s][jl];
                s = s_prev[s];
            }
#pragma unroll
            for (int jl = 0; jl < BN; ++jl) res[jl] += 0.05f * q[jl];  // 0.5*ALP
        }
        float* op = out + (size_t)i * NCLS + j0;
#pragma unroll
        for (int jl = 0; jl < BN; jl += 4) {        // NCLS%4==0 -> exact guard
            if (j0 + jl < NCLS)
                *(float4*)(op + jl) = make_float4(res[jl], res[jl+1], res[jl+2], res[jl+3]);
        }
    }
}

extern "C" void kernel_launch(void* const* d_in, const int* in_sizes, int n_in,
                              void* d_out, int out_size, void* d_ws, size_t ws_size,
                              hipStream_t stream) {
    const float* df = (const float*)d_in[0];
    const int*   gt = (const int*)d_in[1];
    const float* fc = (const float*)d_in[2];
    float* out = (float*)d_out;
    (void)d_ws; (void)ws_size;

    fused_all<<<NBLK, 512, 0, stream>>>(df, gt, fc, out);
}

// Round 7
// 14.726 us; speedup vs baseline: 3.7828x; 3.7828x over previous
//
#include <hip/hip_runtime.h>

#define NCLS 1000
#define NDF  256
#define BB   512
#define O_LD 1024

#define BM 32
#define BN 64
#define BK 32
#define NCHUNK (NDF / BK)   // 8

typedef __attribute__((ext_vector_type(8))) short short8;
typedef __attribute__((ext_vector_type(4))) float floatx4;

static __device__ __forceinline__ unsigned short f2bf(float f) {
    unsigned int u = __float_as_uint(f);
    u += 0x7FFFu + ((u >> 16) & 1u);   // RNE
    return (unsigned short)(u >> 16);
}

// ---------------- K1: G = df . fc^T via bf16 MFMA (verified R5) ----------------
template <bool FULL>
static __device__ __forceinline__ void run_pipe(
    const float* __restrict__ ap, const float* __restrict__ bp, bool bok,
    unsigned short (&Ah)[2][BM][BK], unsigned short (&Bh)[2][BN][BK],
    int arow, int ak, int brow, int bk,
    int r16, int c32, int lr, int lk,
    floatx4& acc0, floatx4& acc1)
{
    float4 va = *(const float4*)ap;
    float4 vb0, vb1;
    if (FULL || bok) { vb0 = *(const float4*)bp; vb1 = *(const float4*)(bp + 4); }
    else { vb0 = make_float4(0.f, 0.f, 0.f, 0.f); vb1 = vb0; }

    *(ushort4*)&Ah[0][arow][ak] =
        make_ushort4(f2bf(va.x), f2bf(va.y), f2bf(va.z), f2bf(va.w));
    *(ushort4*)&Bh[0][brow][bk] =
        make_ushort4(f2bf(vb0.x), f2bf(vb0.y), f2bf(vb0.z), f2bf(vb0.w));
    *(ushort4*)&Bh[0][brow][bk + 4] =
        make_ushort4(f2bf(vb1.x), f2bf(vb1.y), f2bf(vb1.z), f2bf(vb1.w));
    __syncthreads();

    for (int c = 0; c < NCHUNK; ++c) {
        int cur = c & 1;
        float4 na, nb0, nb1;
        if (c + 1 < NCHUNK) {
            int k0 = (c + 1) * BK;
            na = *(const float4*)(ap + k0);
            if (FULL || bok) {
                nb0 = *(const float4*)(bp + k0);
                nb1 = *(const float4*)(bp + k0 + 4);
            } else {
                nb0 = make_float4(0.f, 0.f, 0.f, 0.f); nb1 = nb0;
            }
        }
        short8 a  = *(const short8*)&Ah[cur][r16 + lr][lk];
        short8 b0 = *(const short8*)&Bh[cur][c32 + lr][lk];
        short8 b1 = *(const short8*)&Bh[cur][c32 + 16 + lr][lk];
        acc0 = __builtin_amdgcn_mfma_f32_16x16x32_bf16(a, b0, acc0, 0, 0, 0);
        acc1 = __builtin_amdgcn_mfma_f32_16x16x32_bf16(a, b1, acc1, 0, 0, 0);
        if (c + 1 < NCHUNK) {
            int nxt = cur ^ 1;
            *(ushort4*)&Ah[nxt][arow][ak] =
                make_ushort4(f2bf(na.x), f2bf(na.y), f2bf(na.z), f2bf(na.w));
            *(ushort4*)&Bh[nxt][brow][bk] =
                make_ushort4(f2bf(nb0.x), f2bf(nb0.y), f2bf(nb0.z), f2bf(nb0.w));
            *(ushort4*)&Bh[nxt][brow][bk + 4] =
                make_ushort4(f2bf(nb1.x), f2bf(nb1.y), f2bf(nb1.z), f2bf(nb1.w));
            __syncthreads();
        }
    }
}

__global__ __launch_bounds__(256) void gemm_mfma(const float* __restrict__ df,
                                                 const float* __restrict__ fc,
                                                 float* __restrict__ O) {
    __shared__ unsigned short Ah[2][BM][BK];
    __shared__ unsigned short Bh[2][BN][BK];
    int tid = threadIdx.x;
    int m0 = blockIdx.y * BM;
    int j0 = blockIdx.x * BN;

    int arow = tid >> 3, ak = (tid & 7) * 4;
    int brow = tid >> 2, bk = (tid & 3) * 8;
    const float* ap = df + (size_t)(m0 + arow) * NDF + ak;
    const float* bp = fc + (size_t)(j0 + brow) * NDF + bk;
    bool bok = (j0 + brow) < NCLS;

    int lane = tid & 63, w = tid >> 6;
    int r16 = (w & 1) * 16, c32 = (w >> 1) * 32;
    int lr = lane & 15, lk = (lane >> 4) * 8;

    floatx4 acc0 = {0.f, 0.f, 0.f, 0.f}, acc1 = {0.f, 0.f, 0.f, 0.f};

    if (j0 + BN <= NCLS) {
        run_pipe<true>(ap, bp, bok, Ah, Bh, arow, ak, brow, bk,
                       r16, c32, lr, lk, acc0, acc1);
    } else {
        run_pipe<false>(ap, bp, bok, Ah, Bh, arow, ak, brow, bk,
                        r16, c32, lr, lk, acc0, acc1);
    }

    // C/D layout: col = lane&15, row = (lane>>4)*4 + reg   [m89-verified]
    int orow = m0 + r16 + (lane >> 4) * 4;
    int ocol = j0 + c32 + lr;
#pragma unroll
    for (int r = 0; r < 4; ++r) {
        O[(size_t)(orow + r) * O_LD + ocol]      = acc0[r];
        O[(size_t)(orow + r) * O_LD + ocol + 16] = acc1[r];
    }
}

// ---------------- K2: combine with in-block ballot occurrence scan ----------------
// One block per row i (512 threads). Wave ballots of (gt[k]==gt[i]) give 8x64-bit
// occurrence masks; n = popcount of bits <= i; walk set bits ascending -- same
// arithmetic sequence as the R5 occStep walk. Scalar per-thread state only.
__global__ __launch_bounds__(512) void combine_fused(
    const int* __restrict__ gt, const float* __restrict__ O,
    float* __restrict__ out)
{
    __shared__ unsigned long long masks[8];
    int tid = threadIdx.x;
    int i = blockIdx.x;
    int t = gt[i];                       // broadcast
    int g = gt[tid];                     // coalesced
    unsigned long long bal = __ballot(g == t);
    if ((tid & 63) == 0) masks[tid >> 6] = bal;
    __syncthreads();

    int j = tid * 2;
    if (j >= NCLS) return;               // after the barrier; no barriers below

    // n = #occurrences of class t at positions <= i (always >= 1)
    int n = 0;
#pragma unroll
    for (int wi = 0; wi < 8; ++wi) {
        int d = i - wi * 64;
        unsigned long long mk = masks[wi];
        if (d >= 64)      n += __popcll(mk);
        else if (d >= 0)  n += __popcll(mk & ((2ULL << d) - 1ULL));  // d=63 -> all ones
    }

    const float* Grow = O + (size_t)i * O_LD;
    float2 gv = *(const float2*)&Grow[j];
    float gtv = Grow[t];
    float gx = gv.x - gtv, gy = gv.y - gtv;
    float qx = 0.f, qy = 0.f;

    if (n >= 2) {
        float invn = 1.f / (float)n;
        float Sx = 0.f, Sy = 0.f, St = 0.f;
        int m = 0;
        for (int wi = 0; wi < 8 && m < n; ++wi) {
            unsigned long long mk = masks[wi];
            while (mk && m < n) {
                int b = __builtin_ctzll(mk);
                mk &= mk - 1ULL;
                int s = wi * 64 + b;
                float2 Gsj = *(const float2*)&O[(size_t)s * O_LD + j];
                float Gst = O[(size_t)s * O_LD + t];
                ++m;
                Sx += Gsj.x; Sy += Gsj.y; St += Gst;
                if (m >= 2) {
                    float inv_m = 1.f / (float)m;
                    float ht = Gst - St * inv_m;
                    float hx = (Gsj.x - Sx * inv_m) - ht;
                    float hy = (Gsj.y - Sy * inv_m) - ht;
                    float coef = (float)(m - 1) * inv_m * invn;
                    qx += coef * hx * hx;
                    qy += coef * hy * hy;
                }
            }
        }
    }
    // j even, NCLS even -> float2 store always in-bounds when j < NCLS
    *(float2*)&out[(size_t)i * NCLS + j] =
        make_float2(gx + 0.05f * qx, gy + 0.05f * qy);   // 0.5*ALP = 0.05
}

extern "C" void kernel_launch(void* const* d_in, const int* in_sizes, int n_in,
                              void* d_out, int out_size, void* d_ws, size_t ws_size,
                              hipStream_t stream) {
    const float* df = (const float*)d_in[0];
    const int*   gt = (const int*)d_in[1];
    const float* fc = (const float*)d_in[2];
    float* out = (float*)d_out;

    float* O = (float*)d_ws;   // 512*1024*4 = 2 MB of workspace

    gemm_mfma<<<dim3(16, 16), 256, 0, stream>>>(df, fc, O);
    combine_fused<<<BB, 512, 0, stream>>>(gt, O, out);
}